// Round 16
// baseline (263.996 us; speedup 1.0000x reference)
//
#include <hip/hip_runtime.h>
#include <hip/hip_bf16.h>
#include <math.h>

#define NN 200000
#define NE 200000

typedef __attribute__((ext_vector_type(8))) short bf16x8;
typedef __attribute__((ext_vector_type(4))) float f32x4;

#define XASTR 136   // XA row stride (u16): 128 used
#define XBSTR 296   // XB/PB row stride (u16): other(128)|ef(128)|te(16)|zero(16)|pad(8)
#define OSTR  132   // f32 output-stage row stride (XB reuse)
#define NT    (NN / 32)            // 6250 tiles, exact
#define PBT   (32 * XBSTR)         // 9472 u16 = 18944 B per tile
#define GRID_MAIN 256              // persistent: 1 block per CU

__device__ __forceinline__ float sigm(float x) { return 1.0f / (1.0f + __expf(-x)); }
__device__ __forceinline__ float tanh_f(float x) {
    float e = __expf(2.0f * x);
    return 1.0f - 2.0f / (e + 1.0f);
}
__device__ __forceinline__ ushort f2b(float x) {
    union { __hip_bfloat16 b; ushort u; } v;
    v.b = __float2bfloat16(x);
    return v.u;
}
__device__ __forceinline__ float b2f(ushort u) {
    return __uint_as_float(((unsigned)u) << 16);
}
__device__ __forceinline__ ushort4 cvt4(float4 v) {
    ushort4 u; u.x = f2b(v.x); u.y = f2b(v.y); u.z = f2b(v.z); u.w = f2b(v.w);
    return u;
}
__device__ __forceinline__ void gload_lds16(const ushort* g, ushort* l) {
    __builtin_amdgcn_global_load_lds(
        (const __attribute__((address_space(1))) unsigned int*)g,
        (__attribute__((address_space(3))) unsigned int*)l, 16, 0, 0);
}

#define MFMA16(a, b, c) __builtin_amdgcn_mfma_f32_16x16x32_bf16((a), (b), (c), 0, 0, 0)

// ======== K1: last_pos via atomicMax (== segment_max of positions) ========
__global__ void k_scatter(const int* __restrict__ src, const int* __restrict__ dst,
                          int* __restrict__ last_pos) {
    int i = blockIdx.x * blockDim.x + threadIdx.x;
    if (i < NE) {
        atomicMax(&last_pos[src[i]], i);
    } else if (i < 2 * NE) {
        atomicMax(&last_pos[dst[i - NE]], i);
    }
}

// ======== K2: weight prep (blocks 0..NB_PREP-1) || gather + absent-copy (rest) ========
#define NB_PREP 594                     // ceil((104*512 + 2*96*512 + 384)/256)
#define NB_GATH (NN / 16)               // 4 waves x 4 nodes per block
__global__ __launch_bounds__(256)
void k_pg(const float* __restrict__ W1, const float* __restrict__ W2,
          const float* __restrict__ Wih, const float* __restrict__ Whh,
          const float* __restrict__ b2, const float* __restrict__ bih,
          ushort* __restrict__ W1F, ushort* __restrict__ W2IF,
          ushort* __restrict__ WHF, float* __restrict__ cb,
          const int* __restrict__ last_pos,
          const int* __restrict__ src, const int* __restrict__ dst,
          const float* __restrict__ ts, const float* __restrict__ lut,
          const float* __restrict__ mem, const float* __restrict__ ef,
          const float* __restrict__ tw, const float* __restrict__ tphi,
          ushort* __restrict__ PB, float* __restrict__ out)
{
    int b = blockIdx.x;
    if (b < NB_PREP) {
        int t = b * 256 + threadIdx.x;
        if (t < 104 * 512) {
            int f = t >> 9, idx = t & 511;
            int lane = idx >> 3, j = idx & 7, c16 = lane & 15, k8 = lane >> 4;
            int wvv = f / 26, r = f % 26, kt = r >> 1, ns = r & 1;
            int col = wvv * 32 + ns * 16 + c16;
            int kk = kt * 32 + k8 * 8 + j;
            W1F[t] = (kk < 400) ? f2b(W1[kk * 128 + col]) : (ushort)0;
            return;
        }
        t -= 104 * 512;
        if (t < 96 * 512) {
            int f = t >> 9, idx = t & 511;
            int lane = idx >> 3, j = idx & 7, c16 = lane & 15, k8 = lane >> 4;
            int wvv = f / 24, r = f % 24, kt = r / 6, rem = r % 6, g = rem >> 1, ns = rem & 1;
            int col = g * 128 + wvv * 32 + ns * 16 + c16;
            int kk = kt * 32 + k8 * 8 + j;
            float s = 0.0f;
            for (int c = 0; c < 128; ++c) s = fmaf(W2[kk * 128 + c], Wih[col * 128 + c], s);
            W2IF[f * 512 + idx] = f2b(s);
            return;
        }
        t -= 96 * 512;
        if (t < 96 * 512) {
            int f = t >> 9, idx = t & 511;
            int lane = idx >> 3, j = idx & 7, c16 = lane & 15, k8 = lane >> 4;
            int wvv = f / 24, r = f % 24, kt = r / 6, rem = r % 6, g = rem >> 1, ns = rem & 1;
            int col = g * 128 + wvv * 32 + ns * 16 + c16;
            int kk = kt * 32 + k8 * 8 + j;
            WHF[f * 512 + idx] = f2b(Whh[col * 128 + kk]);
            return;
        }
        t -= 96 * 512;
        if (t < 384) {
            float s = bih[t];
            for (int k = 0; k < 128; ++k) s = fmaf(b2[k], Wih[t * 128 + k], s);
            cb[t] = s;
        }
        return;
    }

    // ---- gather: 4 nodes/wave, all loads issued before any write ----
    const int wv = threadIdx.x >> 6, lane = threadIdx.x & 63;
    const int n0 = (((b - NB_PREP) * 4) + wv) * 4;
    const int l = lane & 31;
    const bool lo = lane < 32;

    int p[4];
    #pragma unroll
    for (int s = 0; s < 4; ++s) p[s] = last_pos[n0 + s];

    float4 mv[4], fv[4];
    float te[4];
    #pragma unroll
    for (int s = 0; s < 4; ++s) {
        te[s] = 0.0f;
        if (p[s] >= 0) {                   // wave-uniform branch
            int e = (p[s] < NE) ? p[s] : p[s] - NE;
            int o = (p[s] < NE) ? dst[e] : src[e];
            if (lo) {
                mv[s] = *(const float4*)&mem[(size_t)o * 128 + l * 4];
                if (l < 16) {
                    float dt = ts[e] - lut[n0 + s];
                    float w = fmaf(dt, tw[l], tphi[l]);
                    te[s] = (l == 0) ? w : __sinf(w);
                }
            } else {
                fv[s] = *(const float4*)&ef[(size_t)e * 128 + l * 4];
            }
        }
    }
    #pragma unroll
    for (int s = 0; s < 4; ++s) {
        if (p[s] >= 0) {
            ushort* xb = PB + (size_t)(n0 + s) * XBSTR;
            if (lo) {
                *(ushort4*)&xb[l * 4] = cvt4(mv[s]);
                xb[256 + l] = (l < 16) ? f2b(te[s]) : (ushort)0;
            } else {
                *(ushort4*)&xb[128 + l * 4] = cvt4(fv[s]);
            }
        } else {
            // absent node: out row = exact f32 copy of mem (coalesced, n consecutive)
            float2 v = *(const float2*)&mem[(size_t)(n0 + s) * 128 + lane * 2];
            *(float2*)&out[(size_t)(n0 + s) * 128 + lane * 2] = v;
        }
    }
}

// ======== K3: persistent main — weights resident in registers, dbuf activations ========
__global__ __launch_bounds__(256, 1)
void k_main12(const ushort* __restrict__ PB, const int* __restrict__ last_pos,
              const float* __restrict__ mem,
              const ushort* __restrict__ W1F, const float* __restrict__ b1,
              const ushort* __restrict__ W2IF, const ushort* __restrict__ WHF,
              const float* __restrict__ cb, const float* __restrict__ bhh,
              float* __restrict__ out)
{
    __shared__ __align__(16) ushort XAd[2][32 * XASTR];   // mem[n] bf16 (dbuf)
    __shared__ __align__(16) ushort XBd[2][32 * XBSTR];   // staged PB (dbuf); XBf overlay
    __shared__ __align__(16) ushort HB[32 * XASTR];       // h1 bf16
    __shared__ unsigned char presd[2][32];

    const int tid  = threadIdx.x;
    const int lane = tid & 63;
    const int wv   = tid >> 6;
    const int r16  = lane & 15;
    const int kb   = lane >> 4;

    // ---- load this wave's full weight slice into registers (once per block) ----
    bf16x8 W1r[26], WIr[24], WHr[24];
    {
        const ushort* w1 = W1F  + wv * (26 * 512) + lane * 8;
        #pragma unroll
        for (int i = 0; i < 26; ++i) W1r[i] = *(const bf16x8*)(w1 + i * 512);
        const ushort* wI = W2IF + wv * (24 * 512) + lane * 8;
        const ushort* wH = WHF  + wv * (24 * 512) + lane * 8;
        #pragma unroll
        for (int i = 0; i < 24; ++i) {
            WIr[i] = *(const bf16x8*)(wI + i * 512);
            WHr[i] = *(const bf16x8*)(wH + i * 512);
        }
    }
    // ---- hoisted biases (constant across tiles) ----
    float b1v[2], brz0[2], brz1[2], binv[2], bhnv[2];
    #pragma unroll
    for (int ns = 0; ns < 2; ++ns) {
        int col = wv * 32 + ns * 16 + r16;
        b1v[ns]  = b1[col];
        brz0[ns] = cb[col] + bhh[col];
        brz1[ns] = cb[128 + col] + bhh[128 + col];
        binv[ns] = cb[256 + col];
        bhnv[ns] = bhh[256 + col];
    }

    // ---- prologue: stage tile t0 into buffer 0 ----
    const int t0 = blockIdx.x;
    {
        const int tile = (NT - 1) - t0;
        const int base = tile * 32;
        const float* msrc = mem + (size_t)base * 128;
        float4 xa[4];
        #pragma unroll
        for (int k = 0; k < 4; ++k) xa[k] = *(const float4*)&msrc[k * 1024 + tid * 4];
        int pr = (tid < 32) ? last_pos[base + tid] : -1;
        const ushort* srcPB = PB + (size_t)tile * PBT;
        #pragma unroll
        for (int j = 0; j < 5; ++j) {
            int cc = wv + j * 4;
            if (cc < 18) gload_lds16(srcPB + cc * 512 + lane * 8, &XBd[0][cc * 512]);
            else if (cc == 18 && lane < 32) gload_lds16(srcPB + cc * 512 + lane * 8, &XBd[0][cc * 512]);
        }
        #pragma unroll
        for (int k = 0; k < 4; ++k) {
            int i0 = k * 1024 + tid * 4;
            *(ushort4*)&XAd[0][(i0 >> 7) * XASTR + (i0 & 127)] = cvt4(xa[k]);
        }
        if (tid < 32) presd[0][tid] = (unsigned char)(pr >= 0);
        asm volatile("s_waitcnt vmcnt(0)" ::: "memory");
        __syncthreads();
    }

    int c = 0;
    for (int t = t0; t < NT; t += GRID_MAIN) {
        const int tile = (NT - 1) - t;
        const int base = tile * 32;
        const int tn = t + GRID_MAIN;
        const ushort* XA = XAd[c];
        const ushort* XB = XBd[c];

        // ---- C1: layer 1  h1 = relu(x @ W1 + b1) ----
        f32x4 c1[2][2] = {};
        {
            const ushort* aA = &XA[r16 * XASTR + kb * 8];
            const ushort* aB = &XB[r16 * XBSTR + kb * 8];
            #pragma unroll
            for (int kt = 0; kt < 13; ++kt) {
                const ushort* ap  = (kt < 4) ? (aA + kt * 32) : (aB + (kt - 4) * 32);
                const int     ast = (kt < 4) ? XASTR : XBSTR;
                bf16x8 A0 = *(const bf16x8*)ap;
                bf16x8 A1 = *(const bf16x8*)(ap + 16 * ast);
                c1[0][0] = MFMA16(A0, W1r[kt * 2 + 0], c1[0][0]);
                c1[0][1] = MFMA16(A0, W1r[kt * 2 + 1], c1[0][1]);
                c1[1][0] = MFMA16(A1, W1r[kt * 2 + 0], c1[1][0]);
                c1[1][1] = MFMA16(A1, W1r[kt * 2 + 1], c1[1][1]);
            }
        }
        // ---- H write -> HB ----
        #pragma unroll
        for (int ns = 0; ns < 2; ++ns) {
            int col = wv * 32 + ns * 16 + r16;
            #pragma unroll
            for (int m = 0; m < 2; ++m)
                #pragma unroll
                for (int r = 0; r < 4; ++r)
                    HB[(m * 16 + kb * 4 + r) * XASTR + col] =
                        f2b(fmaxf(c1[m][ns][r] + b1v[ns], 0.0f));
        }
        __syncthreads();                   // bar2: H visible; XB[c] C1-reads done

        // ---- prefetch tile t+GRID: XA rows into regs FIRST, then XB gloads ----
        float4 xan[4];
        int prn = -1;
        if (tn < NT) {
            const int nbase = ((NT - 1) - tn) * 32;
            const float* msrc = mem + (size_t)nbase * 128;
            #pragma unroll
            for (int k = 0; k < 4; ++k) xan[k] = *(const float4*)&msrc[k * 1024 + tid * 4];
            if (tid < 32) prn = last_pos[nbase + tid];
            const ushort* srcPB = PB + (size_t)((NT - 1) - tn) * PBT;
            #pragma unroll
            for (int j = 0; j < 5; ++j) {
                int cc = wv + j * 4;
                if (cc < 18) gload_lds16(srcPB + cc * 512 + lane * 8, &XBd[c ^ 1][cc * 512]);
                else if (cc == 18 && lane < 32) gload_lds16(srcPB + cc * 512 + lane * 8, &XBd[c ^ 1][cc * 512]);
            }
        }

        // ---- C3+C4: GRU ns-split, weights from registers ----
        float* XBf = (float*)XBd[c];       // XB[c] dead after bar2
        #pragma unroll
        for (int ns = 0; ns < 2; ++ns) {
            f32x4 arz[2][2] = {};
            f32x4 an_i[2] = {};
            f32x4 an_h[2] = {};
            const ushort* am = &HB[r16 * XASTR + kb * 8];
            const ushort* ah = &XA[r16 * XASTR + kb * 8];
            #pragma unroll
            for (int kt = 0; kt < 4; ++kt) {
                bf16x8 M0 = *(const bf16x8*)(am + kt * 32);
                bf16x8 M1 = *(const bf16x8*)(am + 16 * XASTR + kt * 32);
                bf16x8 H0 = *(const bf16x8*)(ah + kt * 32);
                bf16x8 H1 = *(const bf16x8*)(ah + 16 * XASTR + kt * 32);
                #pragma unroll
                for (int s = 0; s < 3; ++s) {
                    bf16x8 Bi = WIr[kt * 6 + s * 2 + ns];
                    bf16x8 Bh = WHr[kt * 6 + s * 2 + ns];
                    if (s < 2) {
                        arz[0][s] = MFMA16(M0, Bi, arz[0][s]);
                        arz[0][s] = MFMA16(H0, Bh, arz[0][s]);
                        arz[1][s] = MFMA16(M1, Bi, arz[1][s]);
                        arz[1][s] = MFMA16(H1, Bh, arz[1][s]);
                    } else {
                        an_i[0] = MFMA16(M0, Bi, an_i[0]);
                        an_i[1] = MFMA16(M1, Bi, an_i[1]);
                        an_h[0] = MFMA16(H0, Bh, an_h[0]);
                        an_h[1] = MFMA16(H1, Bh, an_h[1]);
                    }
                }
            }
            // C4 for this ns: gates + blend -> f32 stage into XB[c]
            #pragma unroll
            for (int m = 0; m < 2; ++m) {
                #pragma unroll
                for (int r = 0; r < 4; ++r) {
                    int row = m * 16 + kb * 4 + r;
                    int col = wv * 32 + ns * 16 + r16;
                    float rr = sigm(arz[m][0][r] + brz0[ns]);
                    float zz = sigm(arz[m][1][r] + brz1[ns]);
                    float nn = tanh_f(an_i[m][r] + binv[ns] + rr * (an_h[m][r] + bhnv[ns]));
                    float hh = b2f(XA[row * XASTR + col]);
                    XBf[row * OSTR + col] = fmaf(zz, hh - nn, nn);   // (1-z)n + zh
                }
            }
        }
        __syncthreads();                   // bar3: out-stage visible

        // ---- C5: coalesced store, present rows only ----
        for (int j = wv; j < 32; j += 4) {
            if (presd[c][j]) {
                float2 v = *(const float2*)&XBf[j * OSTR + lane * 2];
                *(float2*)&out[(size_t)(base + j) * 128 + lane * 2] = v;
            }
        }

        // ---- commit prefetched XA/pres into the spare buffer; drain gloads ----
        if (tn < NT) {
            #pragma unroll
            for (int k = 0; k < 4; ++k) {
                int i0 = k * 1024 + tid * 4;
                *(ushort4*)&XAd[c ^ 1][(i0 >> 7) * XASTR + (i0 & 127)] = cvt4(xan[k]);
            }
            if (tid < 32) presd[c ^ 1][tid] = (unsigned char)(prn >= 0);
        }
        asm volatile("s_waitcnt vmcnt(0)" ::: "memory");
        __syncthreads();                   // next tile's staging visible
        c ^= 1;
    }
}

extern "C" void kernel_launch(void* const* d_in, const int* in_sizes, int n_in,
                              void* d_out, int out_size, void* d_ws, size_t ws_size,
                              hipStream_t stream) {
    const int*   src  = (const int*)d_in[0];
    const int*   dst  = (const int*)d_in[1];
    const float* ef   = (const float*)d_in[2];
    const float* ts   = (const float*)d_in[3];
    const float* mem  = (const float*)d_in[4];
    const float* lut  = (const float*)d_in[5];
    const float* tw   = (const float*)d_in[6];
    const float* tphi = (const float*)d_in[7];
    const float* W1   = (const float*)d_in[8];
    const float* b1   = (const float*)d_in[9];
    const float* W2   = (const float*)d_in[10];
    const float* b2   = (const float*)d_in[11];
    const float* Wih  = (const float*)d_in[12];
    const float* Whh  = (const float*)d_in[13];
    const float* bih  = (const float*)d_in[14];
    const float* bhh  = (const float*)d_in[15];
    float* out = (float*)d_out;

    char* ws = (char*)d_ws;
    size_t off = 0;
    int*    last_pos = (int*)(ws + off);    off += (size_t)NN * 4;
    ushort* W1F      = (ushort*)(ws + off); off += (size_t)104 * 512 * 2;
    ushort* W2IF     = (ushort*)(ws + off); off += (size_t)96 * 512 * 2;
    ushort* WHF      = (ushort*)(ws + off); off += (size_t)96 * 512 * 2;
    float*  cb       = (float*)(ws + off);  off += (size_t)384 * 4 + 64;
    ushort* PB       = (ushort*)(ws + off);   // NN * XBSTR * 2 = 118.4 MB

    hipMemsetAsync(last_pos, 0xFF, (size_t)NN * sizeof(int), stream);  // -1

    k_scatter<<<(2 * NE + 255) / 256, 256, 0, stream>>>(src, dst, last_pos);
    k_pg<<<NB_PREP + NB_GATH, 256, 0, stream>>>(
        W1, W2, Wih, Whh, b2, bih, W1F, W2IF, WHF, cb,
        last_pos, src, dst, ts, lut, mem, ef, tw, tphi, PB, out);
    k_main12<<<GRID_MAIN, 256, 0, stream>>>(PB, last_pos, mem, W1F, b1, W2IF, WHF,
                                            cb, bhh, out);
}